// Round 1
// baseline (392.839 us; speedup 1.0000x reference)
//
#include <hip/hip_runtime.h>
#include <math.h>

#define LRELU_ALPHA 0.2f
#define NEG_BIG -9000000000000000.0f

// d_ws layout (floats): [0,512) wa = W@a ; [512, 512+4096) Wf = bf16 W^T (8192 shorts)
#define WA_OFF 0
#define WF_OFF 512

typedef __attribute__((ext_vector_type(8))) short bf16x8;
typedef __attribute__((ext_vector_type(4))) float f32x4;

static __device__ inline unsigned short f2bf(float x) {
    unsigned int u = __float_as_uint(x);
    unsigned int r = (u + 0x7FFFu + ((u >> 16) & 1u)) >> 16;   // RNE
    return (unsigned short)r;
}

// -------------------------------------------------------------------------
// Kernel 0: prep. Blocks 0..31: Wf[n*128+k] = bf16(W[k][n]) (B-frag-ready
// transpose). Block 32: wa[gi*256 + j*128 + c] = sum_f W[c][f]*a[gi,j*64+f].
// -------------------------------------------------------------------------
__global__ __launch_bounds__(256) void gat_prep_kernel(
    const float* __restrict__ W, const float* __restrict__ a,
    float* __restrict__ ws)
{
    const int tid = threadIdx.x;
    if (blockIdx.x < 32) {
        short* wf = (short*)(ws + WF_OFF);
        const int o = blockIdx.x * 256 + tid;
        const int nn = o >> 7, k = o & 127;
        wf[o] = (short)f2bf(W[k * 64 + nn]);
    } else {
        float* wa = ws + WA_OFF;
        for (int idx = tid; idx < 512; idx += 256) {
            const int gi = idx >> 8, j = (idx >> 7) & 1, c = idx & 127;
            const float* Wr = W + c * 64;
            const float* ar = a + gi * 128 + j * 64;
            float s = 0.f;
#pragma unroll
            for (int f = 0; f < 64; ++f) s = fmaf(Wr[f], ar[f], s);
            wa[idx] = s;
        }
    }
}

// -------------------------------------------------------------------------
// Fused kernel: one block per n (2048 blocks, 4 waves). Wave w owns
// b = 4w..4w+3 at this n. Wave 0 computes both 6x6 att matrices from the
// hv registers it already loaded (b=0 rows k0-5 -> gi0 in half 0; b=1 rows
// k6-11 -> gi1 in half 1), 32-lane butterfly + softmax, writes 288 B LDS.
// One __syncthreads, then P = Att@h (fp32->bf16, per-wave LDS, stride 136)
// and 3x4x4 mfma_f32_16x16x32_bf16 against global Wf. Elu store.
// LDS = 52224 + 288 B -> 3 blocks/CU.
// -------------------------------------------------------------------------
#define PSTR 136
__global__ __launch_bounds__(256) void gat_fused(
    const float* __restrict__ h, const int* __restrict__ adj,
    const float* __restrict__ ws, float* __restrict__ out)
{
    __shared__ __align__(16) short lds[4 * 48 * PSTR];   // 52224 B
    __shared__ float att_lds[2][36];                     // 288 B

    const int tid  = threadIdx.x;
    const int warp = tid >> 6;
    const int lane = tid & 63;
    const int half = lane >> 5;
    const int li   = lane & 31;
    const int n    = blockIdx.x;
    short* Pw = lds + warp * 48 * PSTR;

    // ---- pair-0 h rows: b = warp*4 + half ----
    const float* hb0 = h + (size_t)((warp * 4 + half) * 2048 + n) * 1536 + li * 4;
    float4 hv[12];
#pragma unroll
    for (int r = 0; r < 12; ++r)
        hv[r] = *(const float4*)(hb0 + r * 128);

    // ---- attention (wave 0 only): uses rows already in hv ----
    if (warp == 0) {
        const int gi = half;   // half0: b=0, rows k=0..5 ; half1: b=1, rows k=6..11
        const float4 w1a = *(const float4*)(ws + WA_OFF + gi * 256 + li * 4);
        const float4 w2a = *(const float4*)(ws + WA_OFF + gi * 256 + 128 + li * 4);
        float t1[6], t2[6];
#pragma unroll
        for (int q = 0; q < 6; ++q) {
            const float4 hq = hv[gi * 6 + q];
            t1[q] = hq.x * w1a.x + hq.y * w1a.y + hq.z * w1a.z + hq.w * w1a.w;
            t2[q] = hq.x * w2a.x + hq.y * w2a.y + hq.z * w2a.z + hq.w * w2a.w;
        }
#pragma unroll
        for (int off = 16; off > 0; off >>= 1) {
#pragma unroll
            for (int q = 0; q < 6; ++q) {
                t1[q] += __shfl_xor(t1[q], off, 64);
                t2[q] += __shfl_xor(t2[q], off, 64);
            }
        }
        if (li < 6) {
            const int p = li;
            float s1p = t1[0];
#pragma unroll
            for (int q = 1; q < 6; ++q) { if (p == q) s1p = t1[q]; }
            float row[6];
            float mx = -3.0e38f;
#pragma unroll
            for (int q = 0; q < 6; ++q) {
                float e = s1p + t2[q];
                e = (e > 0.f) ? e : (LRELU_ALPHA * e);
                const int ad = adj[gi * 36 + p * 6 + q];
                const float m = (ad > 0) ? e : NEG_BIG;
                row[q] = m;
                mx = fmaxf(mx, m);
            }
            float sum = 0.f;
#pragma unroll
            for (int q = 0; q < 6; ++q) {
                row[q] = expf(row[q] - mx);
                sum += row[q];
            }
            const float inv = 1.f / sum;
#pragma unroll
            for (int q = 0; q < 6; ++q) att_lds[gi][p * 6 + q] = row[q] * inv;
        }
    }
    __syncthreads();

    // ---- phase 1: P = Att @ h (fp32), pack bf16 into per-wave LDS ----
    for (int pair = 0; pair < 2; ++pair) {
        const int bno = pair * 2 + half;
        if (pair == 1) {
            const float* hb = h + (size_t)((warp * 4 + bno) * 2048 + n) * 1536 + li * 4;
#pragma unroll
            for (int r = 0; r < 12; ++r)
                hv[r] = *(const float4*)(hb + r * 128);
        }
#pragma unroll
        for (int gi = 0; gi < 2; ++gi) {
            float attv[36];
#pragma unroll
            for (int j = 0; j < 9; ++j) {
                const float4 av = *(const float4*)(&att_lds[gi][j * 4]);
                attv[j * 4 + 0] = av.x; attv[j * 4 + 1] = av.y;
                attv[j * 4 + 2] = av.z; attv[j * 4 + 3] = av.w;
            }
#pragma unroll
            for (int p = 0; p < 6; ++p) {
                float ax = 0.f, ay = 0.f, az = 0.f, aw = 0.f;
#pragma unroll
                for (int q = 0; q < 6; ++q) {
                    const float apq = attv[p * 6 + q];
                    const float4 hq = hv[gi * 6 + q];
                    ax = fmaf(apq, hq.x, ax);
                    ay = fmaf(apq, hq.y, ay);
                    az = fmaf(apq, hq.z, az);
                    aw = fmaf(apq, hq.w, aw);
                }
                const int row = bno * 12 + gi * 6 + p;
                ushort4 pk;
                pk.x = f2bf(ax); pk.y = f2bf(ay);
                pk.z = f2bf(az); pk.w = f2bf(aw);
                *(ushort4*)(Pw + row * PSTR + li * 4) = pk;
            }
        }
    }
    // no __syncthreads: P is own-wave data; compiler orders via lgkmcnt.

    // ---- phase 2: MFMA against global Wf ----
    const short* wf = (const short*)(ws + WF_OFF);
    const int col  = lane & 15;
    const int quad = lane >> 4;
    f32x4 acc[3][4];
#pragma unroll
    for (int mt = 0; mt < 3; ++mt)
#pragma unroll
        for (int nt = 0; nt < 4; ++nt)
            acc[mt][nt] = (f32x4){0.f, 0.f, 0.f, 0.f};

#pragma unroll
    for (int ks = 0; ks < 4; ++ks) {
        bf16x8 bfr[4];
#pragma unroll
        for (int nt = 0; nt < 4; ++nt)
            bfr[nt] = *(const bf16x8*)(wf + (nt * 16 + col) * 128 + ks * 32 + quad * 8);
        bf16x8 afr[3];
#pragma unroll
        for (int mt = 0; mt < 3; ++mt)
            afr[mt] = *(const bf16x8*)(Pw + (mt * 16 + col) * PSTR + ks * 32 + quad * 8);
#pragma unroll
        for (int mt = 0; mt < 3; ++mt)
#pragma unroll
            for (int nt = 0; nt < 4; ++nt)
                acc[mt][nt] = __builtin_amdgcn_mfma_f32_16x16x32_bf16(
                    afr[mt], bfr[nt], acc[mt][nt], 0, 0, 0);
    }

    // ---- epilogue: elu + store (C/D: col=lane&15, row=quad*4+reg) ----
    // wave-local row r -> b = warp*4 + r/12, k = r%12 at this n.
    float* ob = out + (size_t)(warp * 4) * 1572864 + (size_t)n * 768;
#pragma unroll
    for (int mt = 0; mt < 3; ++mt)
#pragma unroll
        for (int nt = 0; nt < 4; ++nt)
#pragma unroll
            for (int r = 0; r < 4; ++r) {
                const int row = mt * 16 + quad * 4 + r;
                const int bl = row / 12;
                const int kl = row - bl * 12;
                float v = acc[mt][nt][r];
                v = (v > 0.f) ? v : (expf(v) - 1.f);
                ob[(size_t)bl * 1572864 + kl * 64 + nt * 16 + col] = v;
            }
}

extern "C" void kernel_launch(void* const* d_in, const int* in_sizes, int n_in,
                              void* d_out, int out_size, void* d_ws, size_t ws_size,
                              hipStream_t stream) {
    const float* h   = (const float*)d_in[0];   // (16,2048,12,128) fp32
    const int*   adj = (const int*)d_in[1];     // (2,6,6) int32
    const float* W   = (const float*)d_in[2];   // (128,64) fp32
    const float* a   = (const float*)d_in[3];   // (2,128,1) fp32
    float* out = (float*)d_out;                 // (16,2048,12,64) fp32
    float* ws  = (float*)d_ws;

    hipLaunchKernelGGL(gat_prep_kernel, dim3(33), dim3(256), 0, stream, W, a, ws);
    hipLaunchKernelGGL(gat_fused, dim3(2048), dim3(256), 0, stream, h, adj, ws, out);
}

// Round 2
// 331.323 us; speedup vs baseline: 1.1857x; 1.1857x over previous
//
#include <hip/hip_runtime.h>
#include <math.h>

#define LRELU_ALPHA 0.2f
#define NEG_BIG -9000000000000000.0f

// d_ws layout (floats): [0,147456) att ; [147456,147968) wa = W@a ;
// [147968, +4096) Wf = bf16 W^T (8192 shorts)
#define WA_OFF 147456
#define WF_OFF 147968

typedef __attribute__((ext_vector_type(8))) short bf16x8;
typedef __attribute__((ext_vector_type(4))) float f32x4;

static __device__ inline unsigned short f2bf(float x) {
    unsigned int u = __float_as_uint(x);
    unsigned int r = (u + 0x7FFFu + ((u >> 16) & 1u)) >> 16;   // RNE
    return (unsigned short)r;
}

// -------------------------------------------------------------------------
// Kernel 0: prep. Blocks 0..31: Wf[n*128+k] = bf16(W[k][n]) (B-frag-ready
// transpose). Block 32: wa[gi*256 + j*128 + c] = sum_f W[c][f]*a[gi,j*64+f].
// -------------------------------------------------------------------------
__global__ __launch_bounds__(256) void gat_prep_kernel(
    const float* __restrict__ W, const float* __restrict__ a,
    float* __restrict__ ws)
{
    const int tid = threadIdx.x;
    if (blockIdx.x < 32) {
        short* wf = (short*)(ws + WF_OFF);
        const int o = blockIdx.x * 256 + tid;
        const int n = o >> 7, k = o & 127;
        wf[o] = (short)f2bf(W[k * 64 + n]);
    } else {
        float* wa = ws + WA_OFF;
        for (int idx = tid; idx < 512; idx += 256) {
            const int gi = idx >> 8, j = (idx >> 7) & 1, c = idx & 127;
            const float* Wr = W + c * 64;
            const float* ar = a + gi * 128 + j * 64;
            float s = 0.f;
#pragma unroll
            for (int f = 0; f < 64; ++f) s = fmaf(Wr[f], ar[f], s);
            wa[idx] = s;
        }
    }
}

// -------------------------------------------------------------------------
// Kernel 1: attention weights via wa trick: s1[q] = h_row_q . wa1.
// One wave per (gi, n). 6 rows x float2/lane, 12 butterfly reductions,
// leaky_relu + adj mask + softmax. No LDS, no 6x64 GEMM.
// -------------------------------------------------------------------------
__global__ __launch_bounds__(256) void gat_att_kernel(
    const float* __restrict__ h, const int* __restrict__ adj,
    float* __restrict__ ws)
{
    const int warp = threadIdx.x >> 6;
    const int lane = threadIdx.x & 63;
    const int iw = blockIdx.x * 4 + warp;   // 0..4095
    const int gi = iw >> 11;
    const int n  = iw & 2047;

    const float* wa = ws + WA_OFF;
    const float2 w1 = *(const float2*)(wa + gi * 256 + 2 * lane);
    const float2 w2 = *(const float2*)(wa + gi * 256 + 128 + 2 * lane);
    const float* hp = h + ((size_t)(gi * 2048 + n) * 12 + (size_t)gi * 6) * 128 + 2 * lane;

    float t1[6], t2[6];
#pragma unroll
    for (int q = 0; q < 6; ++q) {
        const float2 hq = *(const float2*)(hp + q * 128);
        t1[q] = hq.x * w1.x + hq.y * w1.y;
        t2[q] = hq.x * w2.x + hq.y * w2.y;
    }
#pragma unroll
    for (int off = 32; off > 0; off >>= 1) {
#pragma unroll
        for (int q = 0; q < 6; ++q) {
            t1[q] += __shfl_xor(t1[q], off, 64);
            t2[q] += __shfl_xor(t2[q], off, 64);
        }
    }

    if (lane < 6) {
        const int p = lane;
        float s1p = t1[0];
#pragma unroll
        for (int q = 1; q < 6; ++q) { if (p == q) s1p = t1[q]; }

        float row[6];
        float mx = -3.0e38f;
#pragma unroll
        for (int q = 0; q < 6; ++q) {
            float e = s1p + t2[q];
            e = (e > 0.f) ? e : (LRELU_ALPHA * e);
            const int ad = adj[gi * 36 + p * 6 + q];
            const float m = (ad > 0) ? e : NEG_BIG;
            row[q] = m;
            mx = fmaxf(mx, m);
        }
        float sum = 0.f;
#pragma unroll
        for (int q = 0; q < 6; ++q) {
            row[q] = expf(row[q] - mx);
            sum += row[q];
        }
        const float inv = 1.f / sum;
        float* op = ws + (size_t)iw * 36 + p * 6;
#pragma unroll
        for (int q = 0; q < 6; ++q) op[q] = row[q] * inv;
    }
}

// -------------------------------------------------------------------------
// Kernel 2: out = elu( (Att @ h) @ W ) via bf16 MFMA. Barrier-free.
// Wave = 4 consecutive (b,n) = 48 rows (contiguous 24KB read / 12KB write).
// Phase 1: fp32 att-combine -> bf16 P in per-wave LDS, row stride 136 shorts.
// Phase 2: B-frags direct from global Wf (L2-hot), 3x4x4 mfma_f32_16x16x32.
// Epilogue: elu -> LDS (Pw reused as f32, stride 68) -> float4 read-back ->
// global_store_dwordx4, 1024 B fully-dense lines (kills partial-line write
// amplification seen in round-1 counters: WRITE_SIZE 294 MB vs 98 MB ideal).
// LDS = 52224 B -> 3 blocks/CU.
// -------------------------------------------------------------------------
#define PSTR 136
__global__ __launch_bounds__(256) void gat_main_mfma(
    const float* __restrict__ h, const float* __restrict__ ws,
    float* __restrict__ out)
{
    __shared__ __align__(16) short lds[4 * 48 * PSTR];   // 52224 B
    const int tid  = threadIdx.x;
    const int warp = tid >> 6;
    const int lane = tid & 63;
    short* Pw = lds + warp * 48 * PSTR;

    const int wave_id = blockIdx.x * 4 + warp;
    const int bn0 = wave_id * 4;
    const int half = lane >> 5;
    const int li   = lane & 31;

    // ---- phase 1: P = Att @ h (fp32), pack bf16 into LDS ----
    for (int pair = 0; pair < 2; ++pair) {
        const int bno = pair * 2 + half;
        const int bn  = bn0 + bno;
        const int n   = bn & 2047;

        const float* hb = h + (size_t)bn * 1536 + li * 4;
        float4 hv[12];
#pragma unroll
        for (int r = 0; r < 12; ++r)
            hv[r] = *(const float4*)(hb + r * 128);

#pragma unroll
        for (int gi = 0; gi < 2; ++gi) {
            const float4* ap = (const float4*)(ws + (size_t)(gi * 2048 + n) * 36);
            float attv[36];
#pragma unroll
            for (int j = 0; j < 9; ++j) {
                const float4 av = ap[j];
                attv[j * 4 + 0] = av.x; attv[j * 4 + 1] = av.y;
                attv[j * 4 + 2] = av.z; attv[j * 4 + 3] = av.w;
            }
#pragma unroll
            for (int p = 0; p < 6; ++p) {
                float ax = 0.f, ay = 0.f, az = 0.f, aw = 0.f;
#pragma unroll
                for (int q = 0; q < 6; ++q) {
                    const float apq = attv[p * 6 + q];
                    const float4 hq = hv[gi * 6 + q];
                    ax = fmaf(apq, hq.x, ax);
                    ay = fmaf(apq, hq.y, ay);
                    az = fmaf(apq, hq.z, az);
                    aw = fmaf(apq, hq.w, aw);
                }
                const int row = bno * 12 + gi * 6 + p;
                ushort4 pk;
                pk.x = f2bf(ax); pk.y = f2bf(ay);
                pk.z = f2bf(az); pk.w = f2bf(aw);
                *(ushort4*)(Pw + row * PSTR + li * 4) = pk;
            }
        }
    }
    // no __syncthreads: P is own-wave data; per-wave DS pipe is in-order.

    // ---- phase 2: MFMA against global Wf ----
    const short* wf = (const short*)(ws + WF_OFF);
    const int col  = lane & 15;
    const int quad = lane >> 4;
    f32x4 acc[3][4];
#pragma unroll
    for (int mt = 0; mt < 3; ++mt)
#pragma unroll
        for (int nt = 0; nt < 4; ++nt)
            acc[mt][nt] = (f32x4){0.f, 0.f, 0.f, 0.f};

#pragma unroll
    for (int ks = 0; ks < 4; ++ks) {
        bf16x8 bfr[4];
#pragma unroll
        for (int nt = 0; nt < 4; ++nt)
            bfr[nt] = *(const bf16x8*)(wf + (nt * 16 + col) * 128 + ks * 32 + quad * 8);
        bf16x8 afr[3];
#pragma unroll
        for (int mt = 0; mt < 3; ++mt)
            afr[mt] = *(const bf16x8*)(Pw + (mt * 16 + col) * PSTR + ks * 32 + quad * 8);
#pragma unroll
        for (int mt = 0; mt < 3; ++mt)
#pragma unroll
            for (int nt = 0; nt < 4; ++nt)
                acc[mt][nt] = __builtin_amdgcn_mfma_f32_16x16x32_bf16(
                    afr[mt], bfr[nt], acc[mt][nt], 0, 0, 0);
    }

    // ---- epilogue: elu -> LDS (Pw as f32, stride 68 = same 13056 B) ----
    // C/D layout: col=lane&15, row=quad*4+reg.
    float* Pf = (float*)Pw;
#pragma unroll
    for (int mt = 0; mt < 3; ++mt)
#pragma unroll
        for (int nt = 0; nt < 4; ++nt)
#pragma unroll
            for (int r = 0; r < 4; ++r) {
                const int row = mt * 16 + quad * 4 + r;
                float v = acc[mt][nt][r];
                v = (v > 0.f) ? v : (expf(v) - 1.f);
                Pf[row * 68 + nt * 16 + col] = v;
            }

    // ---- read back as float4, store 1024 B contiguous per instruction ----
    float* ob = out + (size_t)bn0 * 768;
    const int cg = (lane & 15) * 4;
#pragma unroll
    for (int g = 0; g < 12; ++g) {
        const int row = g * 4 + quad;
        const float4 v = *(const float4*)(Pf + row * 68 + cg);
        *(float4*)(ob + row * 64 + cg) = v;
    }
}

extern "C" void kernel_launch(void* const* d_in, const int* in_sizes, int n_in,
                              void* d_out, int out_size, void* d_ws, size_t ws_size,
                              hipStream_t stream) {
    const float* h   = (const float*)d_in[0];   // (16,2048,12,128) fp32
    const int*   adj = (const int*)d_in[1];     // (2,6,6) int32
    const float* W   = (const float*)d_in[2];   // (128,64) fp32
    const float* a   = (const float*)d_in[3];   // (2,128,1) fp32
    float* out = (float*)d_out;                 // (16,2048,12,64) fp32
    float* ws  = (float*)d_ws;

    hipLaunchKernelGGL(gat_prep_kernel, dim3(33), dim3(256), 0, stream, W, a, ws);
    hipLaunchKernelGGL(gat_att_kernel, dim3(1024), dim3(256), 0, stream, h, adj, ws);
    hipLaunchKernelGGL(gat_main_mfma, dim3(2048), dim3(256), 0, stream, h, ws, out);
}

// Round 4
// 316.247 us; speedup vs baseline: 1.2422x; 1.0477x over previous
//
#include <hip/hip_runtime.h>
#include <math.h>

#define LRELU_ALPHA 0.2f
#define NEG_BIG -9000000000000000.0f

// d_ws layout (floats): [0,147456) att ; [147456,147968) wa = W@a ;
// [147968, +4096) Wf = bf16 W^T (8192 shorts)
#define WA_OFF 147456
#define WF_OFF 147968

typedef __attribute__((ext_vector_type(8))) short bf16x8;
typedef __attribute__((ext_vector_type(4))) float f32x4;

static __device__ inline unsigned short f2bf(float x) {
    unsigned int u = __float_as_uint(x);
    unsigned int r = (u + 0x7FFFu + ((u >> 16) & 1u)) >> 16;   // RNE
    return (unsigned short)r;
}

// -------------------------------------------------------------------------
// Kernel 0: prep. Blocks 0..31: Wf[n*128+k] = bf16(W[k][n]) (B-frag-ready
// transpose). Block 32: wa[gi*256 + j*128 + c] = sum_f W[c][f]*a[gi,j*64+f].
// -------------------------------------------------------------------------
__global__ __launch_bounds__(256) void gat_prep_kernel(
    const float* __restrict__ W, const float* __restrict__ a,
    float* __restrict__ ws)
{
    const int tid = threadIdx.x;
    if (blockIdx.x < 32) {
        short* wf = (short*)(ws + WF_OFF);
        const int o = blockIdx.x * 256 + tid;
        const int n = o >> 7, k = o & 127;
        wf[o] = (short)f2bf(W[k * 64 + n]);
    } else {
        float* wa = ws + WA_OFF;
        for (int idx = tid; idx < 512; idx += 256) {
            const int gi = idx >> 8, j = (idx >> 7) & 1, c = idx & 127;
            const float* Wr = W + c * 64;
            const float* ar = a + gi * 128 + j * 64;
            float s = 0.f;
#pragma unroll
            for (int f = 0; f < 64; ++f) s = fmaf(Wr[f], ar[f], s);
            wa[idx] = s;
        }
    }
}

// -------------------------------------------------------------------------
// Kernel 1: attention weights via wa trick: s1[q] = h_row_q . wa1.
// One wave per (gi, n). 6 rows x float2/lane, 12 butterfly reductions,
// leaky_relu + adj mask + softmax. No LDS, no 6x64 GEMM.
// -------------------------------------------------------------------------
__global__ __launch_bounds__(256) void gat_att_kernel(
    const float* __restrict__ h, const int* __restrict__ adj,
    float* __restrict__ ws)
{
    const int warp = threadIdx.x >> 6;
    const int lane = threadIdx.x & 63;
    const int iw = blockIdx.x * 4 + warp;   // 0..4095
    const int gi = iw >> 11;
    const int n  = iw & 2047;

    const float* wa = ws + WA_OFF;
    const float2 w1 = *(const float2*)(wa + gi * 256 + 2 * lane);
    const float2 w2 = *(const float2*)(wa + gi * 256 + 128 + 2 * lane);
    const float* hp = h + ((size_t)(gi * 2048 + n) * 12 + (size_t)gi * 6) * 128 + 2 * lane;

    float t1[6], t2[6];
#pragma unroll
    for (int q = 0; q < 6; ++q) {
        const float2 hq = *(const float2*)(hp + q * 128);
        t1[q] = hq.x * w1.x + hq.y * w1.y;
        t2[q] = hq.x * w2.x + hq.y * w2.y;
    }
#pragma unroll
    for (int off = 32; off > 0; off >>= 1) {
#pragma unroll
        for (int q = 0; q < 6; ++q) {
            t1[q] += __shfl_xor(t1[q], off, 64);
            t2[q] += __shfl_xor(t2[q], off, 64);
        }
    }

    if (lane < 6) {
        const int p = lane;
        float s1p = t1[0];
#pragma unroll
        for (int q = 1; q < 6; ++q) { if (p == q) s1p = t1[q]; }

        float row[6];
        float mx = -3.0e38f;
#pragma unroll
        for (int q = 0; q < 6; ++q) {
            float e = s1p + t2[q];
            e = (e > 0.f) ? e : (LRELU_ALPHA * e);
            const int ad = adj[gi * 36 + p * 6 + q];
            const float m = (ad > 0) ? e : NEG_BIG;
            row[q] = m;
            mx = fmaxf(mx, m);
        }
        float sum = 0.f;
#pragma unroll
        for (int q = 0; q < 6; ++q) {
            row[q] = expf(row[q] - mx);
            sum += row[q];
        }
        const float inv = 1.f / sum;
        float* op = ws + (size_t)iw * 36 + p * 6;
#pragma unroll
        for (int q = 0; q < 6; ++q) op[q] = row[q] * inv;
    }
}

// -------------------------------------------------------------------------
// Kernel 2: out = elu( (Att @ h) @ W ) via bf16 MFMA.
// OCCUPANCY RESTRUCTURE: block = 4 bn, 4 waves COOPERATE on one shared
// 48-row P tile (13 KB LDS vs 52 KB). Wave w: phase 1 builds P rows
// [12w,12w+12) for bn = blk*4+w (halves split gi; att read as wave-uniform
// LDS broadcast -> no 36-reg attv). One sync. Phase 2: wave w = output
// column nt=w, 3 mt x 4 ks MFMA. Per-thread regs ~50 ->
// __launch_bounds__(256,8): 64 VGPR, 8 blocks/CU = 32 waves/CU (was 12).
// Nontemporal on the h/out streams (no reuse). f32x4 (ext_vector) for the
// nontemporal loads: builtin rejects HIP_vector_type.
// -------------------------------------------------------------------------
#define PSTR 136
__global__ __launch_bounds__(256, 8) void gat_main_mfma(
    const float* __restrict__ h, const float* __restrict__ ws,
    float* __restrict__ out)
{
    __shared__ __align__(16) short Pl[48 * PSTR];    // 13056 B
    __shared__ __align__(16) float attl[288];        // [gi][nn][36], 1152 B

    const int tid  = threadIdx.x;
    const int warp = tid >> 6;
    const int lane = tid & 63;
    const int half = lane >> 5;
    const int li   = lane & 31;
    const int bn0  = blockIdx.x * 4;
    const int n0   = bn0 & 2047;        // blocks never straddle b (2048%4==0)

    // ---- stage att for this block's 4 n (both gi) into LDS ----
    for (int i = tid; i < 288; i += 256) {
        const int gi = i / 144;
        const int rem = i - gi * 144;
        const int nn = rem / 36;
        const int e  = rem - nn * 36;
        attl[i] = ws[(size_t)(gi * 2048 + n0 + nn) * 36 + e];
    }

    // ---- phase 1: wave w builds P rows for bn = bn0 + w ----
    const int bn = bn0 + warp;
    const int gi = half;                 // half-wave splits the two graphs
    const float* hb = h + (size_t)bn * 1536 + gi * 6 * 128 + li * 4;
    f32x4 hv[6];
#pragma unroll
    for (int r = 0; r < 6; ++r)
        hv[r] = __builtin_nontemporal_load((const f32x4*)(hb + r * 128));

    __syncthreads();                     // attl ready

    const float* av = attl + gi * 144 + warp * 36;
#pragma unroll
    for (int p = 0; p < 6; ++p) {
        float ax = 0.f, ay = 0.f, az = 0.f, aw = 0.f;
#pragma unroll
        for (int q = 0; q < 6; ++q) {
            const float apq = av[p * 6 + q];   // wave-uniform LDS broadcast
            const f32x4 hq = hv[q];
            ax = fmaf(apq, hq[0], ax);
            ay = fmaf(apq, hq[1], ay);
            az = fmaf(apq, hq[2], az);
            aw = fmaf(apq, hq[3], aw);
        }
        const int row = warp * 12 + gi * 6 + p;
        ushort4 pk;
        pk.x = f2bf(ax); pk.y = f2bf(ay);
        pk.z = f2bf(az); pk.w = f2bf(aw);
        *(ushort4*)(Pl + row * PSTR + li * 4) = pk;
    }

    __syncthreads();                     // P ready for all waves

    // ---- phase 2: wave w -> output cols [16w,16w+16), 3 mt x 4 ks ----
    const short* wf = (const short*)(ws + WF_OFF);
    const int col  = lane & 15;
    const int quad = lane >> 4;
    f32x4 acc[3];
#pragma unroll
    for (int mt = 0; mt < 3; ++mt) acc[mt] = (f32x4){0.f, 0.f, 0.f, 0.f};

#pragma unroll
    for (int ks = 0; ks < 4; ++ks) {
        const bf16x8 bfr = *(const bf16x8*)(wf + (warp * 16 + col) * 128 + ks * 32 + quad * 8);
#pragma unroll
        for (int mt = 0; mt < 3; ++mt) {
            const bf16x8 afr = *(const bf16x8*)(Pl + (mt * 16 + col) * PSTR + ks * 32 + quad * 8);
            acc[mt] = __builtin_amdgcn_mfma_f32_16x16x32_bf16(afr, bfr, acc[mt], 0, 0, 0);
        }
    }

    // ---- epilogue: elu + store. row -> 64*row within block's 12 KB ----
    // C/D: col=lane&15, row=quad*4+reg. addr = bn0*768 + row*64 + warp*16+col.
    float* ob = out + (size_t)bn0 * 768 + warp * 16 + col;
#pragma unroll
    for (int mt = 0; mt < 3; ++mt)
#pragma unroll
        for (int r = 0; r < 4; ++r) {
            const int row = mt * 16 + quad * 4 + r;
            float v = acc[mt][r];
            v = (v > 0.f) ? v : (expf(v) - 1.f);
            __builtin_nontemporal_store(v, ob + row * 64);
        }
}

extern "C" void kernel_launch(void* const* d_in, const int* in_sizes, int n_in,
                              void* d_out, int out_size, void* d_ws, size_t ws_size,
                              hipStream_t stream) {
    const float* h   = (const float*)d_in[0];   // (16,2048,12,128) fp32
    const int*   adj = (const int*)d_in[1];     // (2,6,6) int32
    const float* W   = (const float*)d_in[2];   // (128,64) fp32
    const float* a   = (const float*)d_in[3];   // (2,128,1) fp32
    float* out = (float*)d_out;                 // (16,2048,12,64) fp32
    float* ws  = (float*)d_ws;

    hipLaunchKernelGGL(gat_prep_kernel, dim3(33), dim3(256), 0, stream, W, a, ws);
    hipLaunchKernelGGL(gat_att_kernel, dim3(1024), dim3(256), 0, stream, h, adj, ws);
    hipLaunchKernelGGL(gat_main_mfma, dim3(8192), dim3(256), 0, stream, h, ws, out);
}